// Round 2
// baseline (532.154 us; speedup 1.0000x reference)
//
#include <hip/hip_runtime.h>

typedef unsigned short u16;
typedef unsigned int u32;
typedef __attribute__((ext_vector_type(8))) short short8;
typedef __attribute__((ext_vector_type(4))) float f32x4;
typedef __attribute__((ext_vector_type(4))) float float4v;
typedef __attribute__((ext_vector_type(4))) unsigned short u16x4;

#define DEV __device__ __forceinline__

DEV u16 f2bf(float f) {
  u32 u = __float_as_uint(f);
  u32 r = (u + 0x7fffu + ((u >> 16) & 1u)) >> 16;
  return (u16)r;
}

DEV f32x4 mfma16(short8 a, short8 b, f32x4 c) {
  return __builtin_amdgcn_mfma_f32_16x16x32_bf16(a, b, c, 0, 0, 0);
}

DEV void gld_lds16(const void* g, void* l) {
  __builtin_amdgcn_global_load_lds(
      (const __attribute__((address_space(1))) void*)g,
      (__attribute__((address_space(3))) void*)l, 16, 0, 0);
}

// ---------------------------------------------------------------------------
// Convert X fp32 -> bf16, linear
__global__ void cvt_x_kernel(const float4v* __restrict__ in,
                             u16x4* __restrict__ out, int n4) {
  int i = blockIdx.x * blockDim.x + threadIdx.x;
  if (i >= n4) return;
  float4v v = in[i];
  u16x4 o;
  o.x = f2bf(v.x); o.y = f2bf(v.y); o.z = f2bf(v.z); o.w = f2bf(v.w);
  out[i] = o;
}

// Convert W fp32 [Kd][Nd] -> bf16 transposed [Nd][Kd]
__global__ void cvt_w_t_kernel(const float* __restrict__ in,
                               u16* __restrict__ out, int Kd, int Nd) {
  __shared__ float tile[32][33];
  int n0 = blockIdx.x * 32, k0 = blockIdx.y * 32;
  int tx = threadIdx.x, ty = threadIdx.y;
#pragma unroll
  for (int j = 0; j < 4; ++j)
    tile[ty + 8 * j][tx] = in[(size_t)(k0 + ty + 8 * j) * Nd + n0 + tx];
  __syncthreads();
#pragma unroll
  for (int j = 0; j < 4; ++j)
    out[(size_t)(n0 + ty + 8 * j) * Kd + k0 + tx] = f2bf(tile[tx][ty + 8 * j]);
}

// ---------------------------------------------------------------------------
// 128x128-tile bf16 GEMM, A [M][K] row-major, Bt [N][K] row-major (B^T).
// LDS: row r chunk j (8 bf16) holds global k-chunk j^(r&7) -> bank-even reads.
// MODE 0: QKV epilogue -> scatter to Q/K/V [B,H,T,D] bf16, Q pre-scaled 0.125
// MODE 1: proj epilogue -> fp32 out [M][N] + bias
template <int MODE>
__global__ __launch_bounds__(256, 2) void gemm_bt(
    const u16* __restrict__ A, const u16* __restrict__ Bt,
    const float* __restrict__ bias, u16* __restrict__ q_out,
    u16* __restrict__ k_out, u16* __restrict__ v_out,
    float* __restrict__ f_out, int M, int N, int K) {
  __shared__ u16 ldsA[128 * 64];
  __shared__ u16 ldsB[128 * 64];
  const int tid = threadIdx.x;
  const int lane = tid & 63, w = tid >> 6;
  const int g = lane >> 4, c = lane & 15;
  const int wm = w >> 1, wn = w & 1;
  const int n0 = blockIdx.x * 128, m0 = blockIdx.y * 128;

  const f32x4 fz = {0.f, 0.f, 0.f, 0.f};
  f32x4 acc[4][4];
#pragma unroll
  for (int i = 0; i < 4; ++i)
#pragma unroll
    for (int j = 0; j < 4; ++j) acc[i][j] = fz;

  const u16* Ag = A + (size_t)m0 * K;
  const u16* Bg = Bt + (size_t)n0 * K;
  const int lr = lane >> 3;       // row within 8-row chunk
  const int kc = (lane & 7) ^ lr; // global k-chunk feeding swizzled LDS slot

  for (int kt = 0; kt < K; kt += 64) {
#pragma unroll
    for (int qq = 0; qq < 4; ++qq) {
      int row = w * 32 + qq * 8 + lr;
      gld_lds16(Ag + (size_t)row * K + kt + kc * 8, &ldsA[(w * 32 + qq * 8) * 64]);
      gld_lds16(Bg + (size_t)row * K + kt + kc * 8, &ldsB[(w * 32 + qq * 8) * 64]);
    }
    __syncthreads();
#pragma unroll
    for (int ks = 0; ks < 2; ++ks) {
      short8 ar[4], br[4];
#pragma unroll
      for (int mr = 0; mr < 4; ++mr) {
        int row = wm * 64 + mr * 16 + c;
        ar[mr] = *(const short8*)&ldsA[row * 64 + (((ks * 4 + g) ^ (row & 7)) << 3)];
      }
#pragma unroll
      for (int nf = 0; nf < 4; ++nf) {
        int row = wn * 64 + nf * 16 + c;
        br[nf] = *(const short8*)&ldsB[row * 64 + (((ks * 4 + g) ^ (row & 7)) << 3)];
      }
#pragma unroll
      for (int mr = 0; mr < 4; ++mr)
#pragma unroll
        for (int nf = 0; nf < 4; ++nf)
          acc[mr][nf] = mfma16(ar[mr], br[nf], acc[mr][nf]);
    }
    __syncthreads();
  }

#pragma unroll
  for (int mr = 0; mr < 4; ++mr) {
#pragma unroll
    for (int nf = 0; nf < 4; ++nf) {
#pragma unroll
      for (int r = 0; r < 4; ++r) {
        int gm = m0 + wm * 64 + mr * 16 + 4 * g + r;
        int gn = n0 + wn * 64 + nf * 16 + c;
        float val = acc[mr][nf][r] + bias[gn];
        if (MODE == 0) {
          int sec = gn >> 10, cc = gn & 1023;
          int hh = cc >> 6, dd = cc & 63;
          int bb = gm >> 11, tt = gm & 2047;
          size_t idx = ((size_t)(bb * 16 + hh) * 2048 + tt) * 64 + dd;
          if (sec == 0)
            q_out[idx] = f2bf(val * 0.125f);
          else if (sec == 1)
            k_out[idx] = f2bf(val);
          else
            v_out[idx] = f2bf(val);
        } else {
          f_out[(size_t)gm * N + gn] = val;
        }
      }
    }
  }
}

// ---------------------------------------------------------------------------
// Flash attention fwd, causal. 1 wave = 16 queries, 4 waves/block (same b,h).
// Q pre-scaled by 1/sqrt(D). Swapped QK^T: s = mfma(Kfrag, Qfrag) so each lane
// holds P values for one query (q = lane&15).
__global__ __launch_bounds__(256, 2) void attn_fwd(
    const u16* __restrict__ Qb, const u16* __restrict__ Kb,
    const u16* __restrict__ Vb, u16* __restrict__ Ob) {
  const int lane = threadIdx.x & 63, w = threadIdx.x >> 6;
  const int g = lane >> 4, c = lane & 15;
  const int bh = blockIdx.x >> 5;
  const int qtile = (blockIdx.x & 31) * 4 + w;
  const int qbase = qtile * 16;
  const int b = bh >> 4, h = bh & 15;
  const size_t base = (size_t)bh * (2048 * 64);
  const u16* Qp = Qb + base;
  const u16* Kp = Kb + base;
  const u16* Vp = Vb + base;

  short8 qf[2];
  qf[0] = *(const short8*)&Qp[(qbase + c) * 64 + g * 8];
  qf[1] = *(const short8*)&Qp[(qbase + c) * 64 + 32 + g * 8];

  const f32x4 fz = {0.f, 0.f, 0.f, 0.f};
  f32x4 o[4];
#pragma unroll
  for (int d0 = 0; d0 < 4; ++d0) o[d0] = fz;
  float m = -1e30f, lsum = 0.f;
  const int qg = qbase + c;
  const int niter = (qbase + 47) >> 5;

  for (int it = 0; it < niter; ++it) {
    const int kb = it << 5;
    const u16* K0 = &Kp[(size_t)(kb + c) * 64 + g * 8];
    short8 k00 = *(const short8*)K0;
    short8 k01 = *(const short8*)(K0 + 32);
    short8 k10 = *(const short8*)(K0 + 16 * 64);
    short8 k11 = *(const short8*)(K0 + 16 * 64 + 32);
    f32x4 s0 = fz, s1 = fz;
    s0 = mfma16(k00, qf[0], s0);
    s0 = mfma16(k01, qf[1], s0);
    s1 = mfma16(k10, qf[0], s1);
    s1 = mfma16(k11, qf[1], s1);

    float p0[4], p1[4], tmax = -1e30f;
#pragma unroll
    for (int r = 0; r < 4; ++r) {
      int kk = kb + 4 * g + r;
      float v0 = (kk <= qg) ? s0[r] : -1e30f;
      float v1 = (kk + 16 <= qg) ? s1[r] : -1e30f;
      p0[r] = v0; p1[r] = v1;
      tmax = fmaxf(tmax, fmaxf(v0, v1));
    }
    tmax = fmaxf(tmax, __shfl_xor(tmax, 16));
    tmax = fmaxf(tmax, __shfl_xor(tmax, 32));
    float mn = fmaxf(m, tmax);
    float sc = __expf(m - mn);
    m = mn;
    float rs = 0.f;
#pragma unroll
    for (int r = 0; r < 4; ++r) {
      p0[r] = __expf(p0[r] - mn);
      p1[r] = __expf(p1[r] - mn);
      rs += p0[r] + p1[r];
    }
    rs += __shfl_xor(rs, 16);
    rs += __shfl_xor(rs, 32);
    lsum = lsum * sc + rs;

    float scr[4];
#pragma unroll
    for (int r = 0; r < 4; ++r) scr[r] = __shfl(sc, 4 * g + r);
#pragma unroll
    for (int d0 = 0; d0 < 4; ++d0)
#pragma unroll
      for (int r = 0; r < 4; ++r) o[d0][r] *= scr[r];

    // redistribute P (C-layout, 4 keys/lane) -> A-operand (8 keys/lane)
    const int sA = 2 * (g & 1);
    float e[8];
#pragma unroll
    for (int r = 0; r < 4; ++r) {
      float x0 = __shfl(p0[r], c + 16 * sA);
      float x1 = __shfl(p0[r], c + 16 * sA + 16);
      float y0 = __shfl(p1[r], c + 16 * sA);
      float y1 = __shfl(p1[r], c + 16 * sA + 16);
      e[r] = (g < 2) ? x0 : y0;
      e[4 + r] = (g < 2) ? x1 : y1;
    }
    short8 pa;
#pragma unroll
    for (int i = 0; i < 8; ++i) pa[i] = (short)f2bf(e[i]);

    const u16* vr = &Vp[(size_t)(kb + 8 * g) * 64 + c];
#pragma unroll
    for (int d0 = 0; d0 < 4; ++d0) {
      short8 vf;
#pragma unroll
      for (int i = 0; i < 8; ++i) vf[i] = (short)vr[i * 64 + d0 * 16];
      o[d0] = mfma16(pa, vf, o[d0]);
    }
  }

  float inv = 1.f / lsum;
  float invr[4];
#pragma unroll
  for (int r = 0; r < 4; ++r) invr[r] = __shfl(inv, 4 * g + r);
  u16* Op = Ob + ((size_t)(b * 2048 + qbase) * 16 + h) * 64;
#pragma unroll
  for (int d0 = 0; d0 < 4; ++d0)
#pragma unroll
    for (int r = 0; r < 4; ++r)
      Op[(size_t)(4 * g + r) * 1024 + d0 * 16 + c] = f2bf(o[d0][r] * invr[r]);
}

// ---------------------------------------------------------------------------
extern "C" void kernel_launch(void* const* d_in, const int* in_sizes, int n_in,
                              void* d_out, int out_size, void* d_ws,
                              size_t ws_size, hipStream_t stream) {
  (void)in_sizes; (void)n_in; (void)out_size; (void)ws_size;
  const float* X = (const float*)d_in[0];
  const float* Wqkv = (const float*)d_in[1];
  const float* bqkv = (const float*)d_in[2];
  const float* Wproj = (const float*)d_in[3];
  const float* bproj = (const float*)d_in[4];
  float* out = (float*)d_out;

  char* ws = (char*)d_ws;
  u16* Xb = (u16*)ws;                          // 16 MiB [8192][1024] bf16 (also O)
  u16* WqkvT = (u16*)(ws + (16u << 20));       // 6 MiB  [3072][1024]
  u16* WprojT = (u16*)(ws + (22u << 20));      // 2 MiB  [1024][1024]
  u16* Qb = (u16*)(ws + (24u << 20));          // 16 MiB [B,H,T,D]
  u16* Kb = (u16*)(ws + (40u << 20));          // 16 MiB
  u16* Vb = (u16*)(ws + (56u << 20));          // 16 MiB (ends at 72 MiB)

  cvt_x_kernel<<<dim3(8192), dim3(256), 0, stream>>>(
      (const float4v*)X, (u16x4*)Xb, 8192 * 1024 / 4);
  cvt_w_t_kernel<<<dim3(96, 32), dim3(32, 8), 0, stream>>>(Wqkv, WqkvT, 1024, 3072);
  cvt_w_t_kernel<<<dim3(32, 32), dim3(32, 8), 0, stream>>>(Wproj, WprojT, 1024, 1024);

  gemm_bt<0><<<dim3(24, 64), dim3(256), 0, stream>>>(
      Xb, WqkvT, bqkv, Qb, Kb, Vb, (float*)nullptr, 8192, 3072, 1024);

  attn_fwd<<<dim3(2048), dim3(256), 0, stream>>>(Qb, Kb, Vb, Xb);

  gemm_bt<1><<<dim3(8, 64), dim3(256), 0, stream>>>(
      Xb, WprojT, bproj, (u16*)nullptr, (u16*)nullptr, (u16*)nullptr, out,
      8192, 1024, 1024);
}

// Round 4
// 464.421 us; speedup vs baseline: 1.1458x; 1.1458x over previous
//
#include <hip/hip_runtime.h>

typedef unsigned short u16;
typedef unsigned int u32;
typedef __attribute__((ext_vector_type(8))) short short8;
typedef __attribute__((ext_vector_type(4))) float f32x4;
typedef __attribute__((ext_vector_type(4))) float float4v;
typedef __attribute__((ext_vector_type(4))) unsigned short u16x4;

#define DEV __device__ __forceinline__

// 0.125 / ln(2): QK^T scale folded with exp->exp2 conversion
#define QSCALE 0.18033688011112042f

DEV u16 f2bf(float f) {
  u32 u = __float_as_uint(f);
  u32 r = (u + 0x7fffu + ((u >> 16) & 1u)) >> 16;
  return (u16)r;
}

DEV u32 packbf2(float lo, float hi) {
  return (u32)f2bf(lo) | ((u32)f2bf(hi) << 16);
}

DEV f32x4 mfma16(short8 a, short8 b, f32x4 c) {
  return __builtin_amdgcn_mfma_f32_16x16x32_bf16(a, b, c, 0, 0, 0);
}

DEV void gld_lds16(const void* g, void* l) {
  __builtin_amdgcn_global_load_lds(
      (const __attribute__((address_space(1))) void*)g,
      (__attribute__((address_space(3))) void*)l, 16, 0, 0);
}

// ---------------------------------------------------------------------------
// Convert X fp32 -> bf16, linear
__global__ void cvt_x_kernel(const float4v* __restrict__ in,
                             u16x4* __restrict__ out, int n4) {
  int i = blockIdx.x * blockDim.x + threadIdx.x;
  if (i >= n4) return;
  float4v v = in[i];
  u16x4 o;
  o.x = f2bf(v.x); o.y = f2bf(v.y); o.z = f2bf(v.z); o.w = f2bf(v.w);
  out[i] = o;
}

// Convert W fp32 [Kd][Nd] -> bf16 transposed [Nd][Kd]
__global__ void cvt_w_t_kernel(const float* __restrict__ in,
                               u16* __restrict__ out, int Kd, int Nd) {
  __shared__ float tile[32][33];
  int n0 = blockIdx.x * 32, k0 = blockIdx.y * 32;
  int tx = threadIdx.x, ty = threadIdx.y;
#pragma unroll
  for (int j = 0; j < 4; ++j)
    tile[ty + 8 * j][tx] = in[(size_t)(k0 + ty + 8 * j) * Nd + n0 + tx];
  __syncthreads();
#pragma unroll
  for (int j = 0; j < 4; ++j)
    out[(size_t)(n0 + ty + 8 * j) * Kd + k0 + tx] = f2bf(tile[tx][ty + 8 * j]);
}

// ---------------------------------------------------------------------------
// 128x128-tile bf16 GEMM, A [M][K] row-major, Bt [N][K] row-major (B^T).
// LDS: row r chunk j (8 bf16) holds global k-chunk j^(r&7) -> bank-even reads.
// MODE 0: QKV epilogue -> Q [bh][t][d] (pre-scaled QSCALE), K [bh][t][d],
//         V transposed [bh][d][t], all bf16
// MODE 1: proj epilogue -> fp32 out [M][N] + bias
template <int MODE>
__global__ __launch_bounds__(256, 2) void gemm_bt(
    const u16* __restrict__ A, const u16* __restrict__ Bt,
    const float* __restrict__ bias, u16* __restrict__ q_out,
    u16* __restrict__ k_out, u16* __restrict__ vt_out,
    float* __restrict__ f_out, int M, int N, int K) {
  __shared__ u16 ldsA[128 * 64];
  __shared__ u16 ldsB[128 * 64];
  const int tid = threadIdx.x;
  const int lane = tid & 63, w = tid >> 6;
  const int g = lane >> 4, c = lane & 15;
  const int wm = w >> 1, wn = w & 1;
  const int n0 = blockIdx.x * 128, m0 = blockIdx.y * 128;

  const f32x4 fz = {0.f, 0.f, 0.f, 0.f};
  f32x4 acc[4][4];
#pragma unroll
  for (int i = 0; i < 4; ++i)
#pragma unroll
    for (int j = 0; j < 4; ++j) acc[i][j] = fz;

  const u16* Ag = A + (size_t)m0 * K;
  const u16* Bg = Bt + (size_t)n0 * K;
  const int lr = lane >> 3;       // row within 8-row chunk
  const int kc = (lane & 7) ^ lr; // global k-chunk feeding swizzled LDS slot

  for (int kt = 0; kt < K; kt += 64) {
#pragma unroll
    for (int qq = 0; qq < 4; ++qq) {
      int row = w * 32 + qq * 8 + lr;
      gld_lds16(Ag + (size_t)row * K + kt + kc * 8, &ldsA[(w * 32 + qq * 8) * 64]);
      gld_lds16(Bg + (size_t)row * K + kt + kc * 8, &ldsB[(w * 32 + qq * 8) * 64]);
    }
    __syncthreads();
#pragma unroll
    for (int ks = 0; ks < 2; ++ks) {
      short8 ar[4], br[4];
#pragma unroll
      for (int mr = 0; mr < 4; ++mr) {
        int row = wm * 64 + mr * 16 + c;
        ar[mr] = *(const short8*)&ldsA[row * 64 + (((ks * 4 + g) ^ (row & 7)) << 3)];
      }
#pragma unroll
      for (int nf = 0; nf < 4; ++nf) {
        int row = wn * 64 + nf * 16 + c;
        br[nf] = *(const short8*)&ldsB[row * 64 + (((ks * 4 + g) ^ (row & 7)) << 3)];
      }
#pragma unroll
      for (int mr = 0; mr < 4; ++mr)
#pragma unroll
        for (int nf = 0; nf < 4; ++nf)
          acc[mr][nf] = mfma16(ar[mr], br[nf], acc[mr][nf]);
    }
    __syncthreads();
  }

#pragma unroll
  for (int mr = 0; mr < 4; ++mr) {
#pragma unroll
    for (int nf = 0; nf < 4; ++nf) {
#pragma unroll
      for (int r = 0; r < 4; ++r) {
        int gm = m0 + wm * 64 + mr * 16 + 4 * g + r;
        int gn = n0 + wn * 64 + nf * 16 + c;
        float val = acc[mr][nf][r] + bias[gn];
        if (MODE == 0) {
          int sec = gn >> 10, cc = gn & 1023;
          int hh = cc >> 6, dd = cc & 63;
          int bb = gm >> 11, tt = gm & 2047;
          if (sec == 0)
            q_out[((size_t)(bb * 16 + hh) * 2048 + tt) * 64 + dd] =
                f2bf(val * QSCALE);
          else if (sec == 1)
            k_out[((size_t)(bb * 16 + hh) * 2048 + tt) * 64 + dd] = f2bf(val);
          else
            vt_out[((size_t)(bb * 16 + hh) * 64 + dd) * 2048 + tt] = f2bf(val);
        } else {
          f_out[(size_t)gm * N + gn] = val;
        }
      }
    }
  }
}

// ---------------------------------------------------------------------------
// Flash attention fwd, causal. 1 wave = 16 queries, 64 keys/iter.
// Swapped QK^T: s = mfma(K, Q) -> C-layout col = query = (lane&15), so all
// softmax state is lane-local. PV uses V^T: o = mfma(V^Tfrag, Pfrag) giving
// O^T (row=d, col=q). Q pre-scaled by 0.125/ln2; exp2-based softmax.
__global__ __launch_bounds__(256, 4) void attn_fwd(
    const u16* __restrict__ Qb, const u16* __restrict__ Kb,
    const u16* __restrict__ VTb, u16* __restrict__ Ob) {
  const int lane = threadIdx.x & 63, w = threadIdx.x >> 6;
  const int g = lane >> 4, c = lane & 15;
  const int bh = blockIdx.x & 63;
  const int qc = 31 - (blockIdx.x >> 6);   // longest blocks launch first
  const int qbase = (qc * 4 + w) * 16;
  const int b = bh >> 4, h = bh & 15;
  const size_t base = (size_t)bh * (2048 * 64);
  const u16* Qp = Qb + base;
  const u16* Kp = Kb + base;
  const u16* VTp = VTb + base;

  short8 qf0 = *(const short8*)&Qp[(qbase + c) * 64 + g * 8];
  short8 qf1 = *(const short8*)&Qp[(qbase + c) * 64 + 32 + g * 8];

  const f32x4 fz = {0.f, 0.f, 0.f, 0.f};
  f32x4 o[4];
#pragma unroll
  for (int d0 = 0; d0 < 4; ++d0) o[d0] = fz;
  float m = -1e30f, lsum = 0.f;
  const int qg = qbase + c;
  const int niter = (qbase + 79) >> 6;  // 64-key tiles covering keys <= qbase+15

  for (int it = 0; it < niter; ++it) {
    const int k0b = it << 6;
    const u16* Kt = Kp + (size_t)k0b * 64;

    // --- QK^T: 64 keys x 16 queries ---
    short8 kA[4], kB[4];
#pragma unroll
    for (int j = 0; j < 4; ++j) {
      kA[j] = *(const short8*)&Kt[(16 * j + c) * 64 + 8 * g];
      kB[j] = *(const short8*)&Kt[(16 * j + c) * 64 + 32 + 8 * g];
    }
    float pv[16];
#pragma unroll
    for (int j = 0; j < 4; ++j) {
      f32x4 s = mfma16(kA[j], qf0, fz);
      s = mfma16(kB[j], qf1, s);
#pragma unroll
      for (int r = 0; r < 4; ++r) pv[j * 4 + r] = s[r];
    }

    if (it == niter - 1) {  // only last tile can contain masked keys
#pragma unroll
      for (int j = 0; j < 4; ++j)
#pragma unroll
        for (int r = 0; r < 4; ++r)
          if (k0b + 16 * j + 4 * g + r > qg) pv[j * 4 + r] = -1e30f;
    }

    // --- online softmax (state lane-local: q = c) ---
    float tm = pv[0];
#pragma unroll
    for (int i = 1; i < 16; ++i) tm = fmaxf(tm, pv[i]);
    tm = fmaxf(tm, __shfl_xor(tm, 16));
    tm = fmaxf(tm, __shfl_xor(tm, 32));
    float mn = fmaxf(m, tm);
    float sc = __builtin_amdgcn_exp2f(m - mn);
    m = mn;
    float rs = 0.f;
#pragma unroll
    for (int i = 0; i < 16; ++i) {
      pv[i] = __builtin_amdgcn_exp2f(pv[i] - mn);
      rs += pv[i];
    }
    rs += __shfl_xor(rs, 16);
    rs += __shfl_xor(rs, 32);
    lsum = lsum * sc + rs;
#pragma unroll
    for (int d0 = 0; d0 < 4; ++d0)
#pragma unroll
      for (int r = 0; r < 4; ++r) o[d0][r] *= sc;

    // --- pack P to bf16 pairs: P2[j*2+rr] = keys (16j+4g+2rr, +1) ---
    u32 P2[8];
#pragma unroll
    for (int j = 0; j < 4; ++j) {
      P2[j * 2 + 0] = packbf2(pv[j * 4 + 0], pv[j * 4 + 1]);
      P2[j * 2 + 1] = packbf2(pv[j * 4 + 2], pv[j * 4 + 3]);
    }

    // --- PV: o^T += V^T @ P, 2 key-halves x 4 d-blocks ---
#pragma unroll
    for (int hh = 0; hh < 2; ++hh) {
      // B-operand: lane (c,g) holds keys k0b+32hh+8g..+7 of query c
      u32 pbw[4];
#pragma unroll
      for (int i = 0; i < 4; ++i) {
        int src = c + ((2 * (g & 1) + (i >> 1)) << 4);
        int a0 = __shfl((int)P2[(2 * hh) * 2 + (i & 1)], src);
        int a1 = __shfl((int)P2[(2 * hh + 1) * 2 + (i & 1)], src);
        pbw[i] = (g < 2) ? (u32)a0 : (u32)a1;
      }
      short8 pb = *(short8*)pbw;
      const u16* Vt = VTp + k0b + 32 * hh + 8 * g;
#pragma unroll
      for (int d0 = 0; d0 < 4; ++d0) {
        short8 va = *(const short8*)&Vt[(size_t)(d0 * 16 + c) * 2048];
        o[d0] = mfma16(va, pb, o[d0]);
      }
    }
  }

  // --- normalize + write: lane holds O[q=c][d = d0*16+4g+r] ---
  float inv = 1.f / lsum;
  u16* Op = Ob + (size_t)(b * 2048 + qbase + c) * 1024 + h * 64;
#pragma unroll
  for (int d0 = 0; d0 < 4; ++d0) {
    u16x4 wv;
#pragma unroll
    for (int r = 0; r < 4; ++r) wv[r] = f2bf(o[d0][r] * inv);
    *(u16x4*)(Op + d0 * 16 + 4 * g) = wv;
  }
}

// ---------------------------------------------------------------------------
extern "C" void kernel_launch(void* const* d_in, const int* in_sizes, int n_in,
                              void* d_out, int out_size, void* d_ws,
                              size_t ws_size, hipStream_t stream) {
  (void)in_sizes; (void)n_in; (void)out_size; (void)ws_size;
  const float* X = (const float*)d_in[0];
  const float* Wqkv = (const float*)d_in[1];
  const float* bqkv = (const float*)d_in[2];
  const float* Wproj = (const float*)d_in[3];
  const float* bproj = (const float*)d_in[4];
  float* out = (float*)d_out;

  char* ws = (char*)d_ws;
  u16* Xb = (u16*)ws;                          // 16 MiB [8192][1024] bf16 (also O)
  u16* WqkvT = (u16*)(ws + (16u << 20));       // 6 MiB  [3072][1024]
  u16* WprojT = (u16*)(ws + (22u << 20));      // 2 MiB  [1024][1024]
  u16* Qb = (u16*)(ws + (24u << 20));          // 16 MiB [bh][t][d], pre-scaled
  u16* Kb = (u16*)(ws + (40u << 20));          // 16 MiB [bh][t][d]
  u16* VT = (u16*)(ws + (56u << 20));          // 16 MiB [bh][d][t]

  cvt_x_kernel<<<dim3(8192), dim3(256), 0, stream>>>(
      (const float4v*)X, (u16x4*)Xb, 8192 * 1024 / 4);
  cvt_w_t_kernel<<<dim3(96, 32), dim3(32, 8), 0, stream>>>(Wqkv, WqkvT, 1024, 3072);
  cvt_w_t_kernel<<<dim3(32, 32), dim3(32, 8), 0, stream>>>(Wproj, WprojT, 1024, 1024);

  gemm_bt<0><<<dim3(24, 64), dim3(256), 0, stream>>>(
      Xb, WqkvT, bqkv, Qb, Kb, VT, (float*)nullptr, 8192, 3072, 1024);

  attn_fwd<<<dim3(2048), dim3(256), 0, stream>>>(Qb, Kb, VT, Xb);

  gemm_bt<1><<<dim3(8, 64), dim3(256), 0, stream>>>(
      Xb, WprojT, bproj, (u16*)nullptr, (u16*)nullptr, (u16*)nullptr, out,
      8192, 1024, 1024);
}

// Round 5
// 291.866 us; speedup vs baseline: 1.8233x; 1.5912x over previous
//
#include <hip/hip_runtime.h>

typedef unsigned short u16;
typedef unsigned int u32;
typedef __attribute__((ext_vector_type(8))) short short8;
typedef __attribute__((ext_vector_type(4))) float f32x4;
typedef __attribute__((ext_vector_type(4))) float float4v;
typedef __attribute__((ext_vector_type(4))) unsigned short u16x4;

#define DEV __device__ __forceinline__

// 0.125 / ln(2): QK^T scale folded with exp->exp2 conversion
#define QSCALE 0.18033688011112042f

DEV u16 f2bf(float f) {
  u32 u = __float_as_uint(f);
  u32 r = (u + 0x7fffu + ((u >> 16) & 1u)) >> 16;
  return (u16)r;
}

DEV u32 packbf2(float lo, float hi) {
  return (u32)f2bf(lo) | ((u32)f2bf(hi) << 16);
}

DEV f32x4 mfma16(short8 a, short8 b, f32x4 c) {
  return __builtin_amdgcn_mfma_f32_16x16x32_bf16(a, b, c, 0, 0, 0);
}

DEV void gld_lds16(const void* g, void* l) {
  __builtin_amdgcn_global_load_lds(
      (const __attribute__((address_space(1))) void*)g,
      (__attribute__((address_space(3))) void*)l, 16, 0, 0);
}

// ---------------------------------------------------------------------------
// Convert X fp32 -> bf16, linear
__global__ void cvt_x_kernel(const float4v* __restrict__ in,
                             u16x4* __restrict__ out, int n4) {
  int i = blockIdx.x * blockDim.x + threadIdx.x;
  if (i >= n4) return;
  float4v v = in[i];
  u16x4 o;
  o.x = f2bf(v.x); o.y = f2bf(v.y); o.z = f2bf(v.z); o.w = f2bf(v.w);
  out[i] = o;
}

// Convert W fp32 [Kd][Nd] -> bf16 transposed [Nd][Kd]
__global__ void cvt_w_t_kernel(const float* __restrict__ in,
                               u16* __restrict__ out, int Kd, int Nd) {
  __shared__ float tile[32][33];
  int n0 = blockIdx.x * 32, k0 = blockIdx.y * 32;
  int tx = threadIdx.x, ty = threadIdx.y;
#pragma unroll
  for (int j = 0; j < 4; ++j)
    tile[ty + 8 * j][tx] = in[(size_t)(k0 + ty + 8 * j) * Nd + n0 + tx];
  __syncthreads();
#pragma unroll
  for (int j = 0; j < 4; ++j)
    out[(size_t)(n0 + ty + 8 * j) * Kd + k0 + tx] = f2bf(tile[tx][ty + 8 * j]);
}

// ---------------------------------------------------------------------------
// 128x128-tile bf16 GEMM, A [M][K] row-major, Bt [N][K] row-major (B^T).
// LDS: row r chunk j (8 bf16) holds global k-chunk j^(r&7) -> bank-even reads.
// MODE 0: QKV epilogue -> Q [bh][t][d] (pre-scaled QSCALE), K [bh][t][d],
//         V transposed [bh][d][t], all bf16
// MODE 1: proj epilogue -> fp32 out [M][N] + bias
template <int MODE>
__global__ __launch_bounds__(256, 2) void gemm_bt(
    const u16* __restrict__ A, const u16* __restrict__ Bt,
    const float* __restrict__ bias, u16* __restrict__ q_out,
    u16* __restrict__ k_out, u16* __restrict__ vt_out,
    float* __restrict__ f_out, int M, int N, int K) {
  __shared__ u16 ldsA[128 * 64];
  __shared__ u16 ldsB[128 * 64];
  const int tid = threadIdx.x;
  const int lane = tid & 63, w = tid >> 6;
  const int g = lane >> 4, c = lane & 15;
  const int wm = w >> 1, wn = w & 1;
  const int n0 = blockIdx.x * 128, m0 = blockIdx.y * 128;

  const f32x4 fz = {0.f, 0.f, 0.f, 0.f};
  f32x4 acc[4][4];
#pragma unroll
  for (int i = 0; i < 4; ++i)
#pragma unroll
    for (int j = 0; j < 4; ++j) acc[i][j] = fz;

  const u16* Ag = A + (size_t)m0 * K;
  const u16* Bg = Bt + (size_t)n0 * K;
  const int lr = lane >> 3;       // row within 8-row chunk
  const int kc = (lane & 7) ^ lr; // global k-chunk feeding swizzled LDS slot

  for (int kt = 0; kt < K; kt += 64) {
#pragma unroll
    for (int qq = 0; qq < 4; ++qq) {
      int row = w * 32 + qq * 8 + lr;
      gld_lds16(Ag + (size_t)row * K + kt + kc * 8, &ldsA[(w * 32 + qq * 8) * 64]);
      gld_lds16(Bg + (size_t)row * K + kt + kc * 8, &ldsB[(w * 32 + qq * 8) * 64]);
    }
    __syncthreads();
#pragma unroll
    for (int ks = 0; ks < 2; ++ks) {
      short8 ar[4], br[4];
#pragma unroll
      for (int mr = 0; mr < 4; ++mr) {
        int row = wm * 64 + mr * 16 + c;
        ar[mr] = *(const short8*)&ldsA[row * 64 + (((ks * 4 + g) ^ (row & 7)) << 3)];
      }
#pragma unroll
      for (int nf = 0; nf < 4; ++nf) {
        int row = wn * 64 + nf * 16 + c;
        br[nf] = *(const short8*)&ldsB[row * 64 + (((ks * 4 + g) ^ (row & 7)) << 3)];
      }
#pragma unroll
      for (int mr = 0; mr < 4; ++mr)
#pragma unroll
        for (int nf = 0; nf < 4; ++nf)
          acc[mr][nf] = mfma16(ar[mr], br[nf], acc[mr][nf]);
    }
    __syncthreads();
  }

#pragma unroll
  for (int mr = 0; mr < 4; ++mr) {
#pragma unroll
    for (int nf = 0; nf < 4; ++nf) {
#pragma unroll
      for (int r = 0; r < 4; ++r) {
        int gm = m0 + wm * 64 + mr * 16 + 4 * g + r;
        int gn = n0 + wn * 64 + nf * 16 + c;
        float val = acc[mr][nf][r] + bias[gn];
        if (MODE == 0) {
          int sec = gn >> 10, cc = gn & 1023;
          int hh = cc >> 6, dd = cc & 63;
          int bb = gm >> 11, tt = gm & 2047;
          if (sec == 0)
            q_out[((size_t)(bb * 16 + hh) * 2048 + tt) * 64 + dd] =
                f2bf(val * QSCALE);
          else if (sec == 1)
            k_out[((size_t)(bb * 16 + hh) * 2048 + tt) * 64 + dd] = f2bf(val);
          else
            vt_out[((size_t)(bb * 16 + hh) * 64 + dd) * 2048 + tt] = f2bf(val);
        } else {
          f_out[(size_t)gm * N + gn] = val;
        }
      }
    }
  }
}

// ---------------------------------------------------------------------------
// Flash attention fwd, causal. Block = 64 queries of one (b,h); 4 waves x 16q.
// Uniform key range per block (niter = qblock+1) -> cooperative LDS staging of
// K tile [64k][64d] and V^T tile [64d][64k] per iteration, double-buffered,
// chunk-XOR swizzled (global source pre-swizzled; ds_read applies same XOR).
// Swapped QK^T: s = mfma(K, Q) -> softmax state lane-local (q = lane&15).
// PV: o^T = mfma(V^Tfrag, Pfrag). Q pre-scaled 0.125/ln2; exp2 softmax.
__global__ __launch_bounds__(256, 4) void attn_fwd(
    const u16* __restrict__ Qb, const u16* __restrict__ Kb,
    const u16* __restrict__ VTb, u16* __restrict__ Ob) {
  __shared__ u16 lds[2][8192];  // per buf: K at [0..4095], VT at [4096..8191]
  const int lane = threadIdx.x & 63, w = threadIdx.x >> 6;
  const int g = lane >> 4, c = lane & 15;
  const int bi = blockIdx.x;
  const int bh = ((bi & 7) << 3) | ((bi >> 3) & 7);  // 8 heads per XCD
  const int qblock = 31 - (bi >> 6);                 // longest blocks first
  const int b = bh >> 4, h = bh & 15;
  const size_t base = (size_t)bh * (2048 * 64);
  const u16* Qp = Qb + base;
  const u16* Kp = Kb + base;
  const u16* VTp = VTb + base;

  const int qw = qblock * 64 + w * 16;  // wave's first query
  const int qg = qw + c;                // this lane's query
  const int nt = qblock + 1;

  short8 qf0 = *(const short8*)&Qp[(qw + c) * 64 + g * 8];
  short8 qf1 = *(const short8*)&Qp[(qw + c) * 64 + 32 + g * 8];

  const f32x4 fz = {0.f, 0.f, 0.f, 0.f};
  f32x4 o[4];
#pragma unroll
  for (int d0 = 0; d0 < 4; ++d0) o[d0] = fz;
  float m = -1e30f, lsum = 0.f;

  // staging: 16 wave-calls of 1KB; region i<8 = K rows 8i..8i+7, i>=8 = VT rows
  const int srow = lane >> 3;                    // row within 8-row region
  const int sgx = (lane & 7) ^ (srow & 7);       // pre-swizzled global chunk
  auto stage = [&](int t, int buf) {
#pragma unroll
    for (int q = 0; q < 4; ++q) {
      const int i = w * 4 + q;
      const int row = ((i & 7) << 3) | srow;
      const int k0 = t << 6;
      const u16* src = (i < 8)
          ? Kp + (size_t)(k0 + row) * 64 + sgx * 8
          : VTp + (size_t)row * 2048 + k0 + sgx * 8;
      gld_lds16(src, &lds[buf][i * 512]);
    }
  };

  stage(0, 0);
  __syncthreads();

  for (int t = 0; t < nt; ++t) {
    const int cur = t & 1;
    if (t + 1 < nt) stage(t + 1, cur ^ 1);
    const u16* Kl = &lds[cur][0];
    const u16* Vl = &lds[cur][4096];
    const int k0b = t << 6;
    const int cx = c & 7;

    // --- QK^T: 64 keys x 16 queries ---
    float pv[16];
#pragma unroll
    for (int j = 0; j < 4; ++j) {
      short8 ka = *(const short8*)&Kl[(16 * j + c) * 64 + ((g ^ cx) << 3)];
      short8 kb = *(const short8*)&Kl[(16 * j + c) * 64 + (((4 + g) ^ cx) << 3)];
      f32x4 s = mfma16(ka, qf0, fz);
      s = mfma16(kb, qf1, s);
#pragma unroll
      for (int r = 0; r < 4; ++r) pv[j * 4 + r] = s[r];
    }

    if (t == nt - 1) {  // only last tile can contain masked keys
#pragma unroll
      for (int j = 0; j < 4; ++j)
#pragma unroll
        for (int r = 0; r < 4; ++r)
          if (k0b + 16 * j + 4 * g + r > qg) pv[j * 4 + r] = -1e30f;
    }

    // --- online softmax (state lane-local: q = c), tree reductions ---
    float mx[8];
#pragma unroll
    for (int i = 0; i < 8; ++i) mx[i] = fmaxf(pv[2 * i], pv[2 * i + 1]);
#pragma unroll
    for (int i = 0; i < 4; ++i) mx[i] = fmaxf(mx[i], mx[i + 4]);
    float tm = fmaxf(fmaxf(mx[0], mx[1]), fmaxf(mx[2], mx[3]));
    tm = fmaxf(tm, __shfl_xor(tm, 16));
    tm = fmaxf(tm, __shfl_xor(tm, 32));
    float mn = fmaxf(m, tm);
    float sc = __builtin_amdgcn_exp2f(m - mn);
    m = mn;
#pragma unroll
    for (int i = 0; i < 16; ++i) pv[i] = __builtin_amdgcn_exp2f(pv[i] - mn);
    float sx[8];
#pragma unroll
    for (int i = 0; i < 8; ++i) sx[i] = pv[2 * i] + pv[2 * i + 1];
#pragma unroll
    for (int i = 0; i < 4; ++i) sx[i] = sx[i] + sx[i + 4];
    float rs = (sx[0] + sx[1]) + (sx[2] + sx[3]);
    rs += __shfl_xor(rs, 16);
    rs += __shfl_xor(rs, 32);
    lsum = lsum * sc + rs;
#pragma unroll
    for (int d0 = 0; d0 < 4; ++d0)
#pragma unroll
      for (int r = 0; r < 4; ++r) o[d0][r] *= sc;

    // --- pack P to bf16 pairs: P2[j*2+rr] = keys (16j+4g+2rr, +1) ---
    u32 P2[8];
#pragma unroll
    for (int j = 0; j < 4; ++j) {
      P2[j * 2 + 0] = packbf2(pv[j * 4 + 0], pv[j * 4 + 1]);
      P2[j * 2 + 1] = packbf2(pv[j * 4 + 2], pv[j * 4 + 3]);
    }

    // --- PV: o^T += V^T @ P, 2 key-halves x 4 d-blocks ---
#pragma unroll
    for (int hh = 0; hh < 2; ++hh) {
      u32 pbw[4];
#pragma unroll
      for (int i = 0; i < 4; ++i) {
        int src = c + ((2 * (g & 1) + (i >> 1)) << 4);
        int a0 = __shfl((int)P2[(2 * hh) * 2 + (i & 1)], src);
        int a1 = __shfl((int)P2[(2 * hh + 1) * 2 + (i & 1)], src);
        pbw[i] = (g < 2) ? (u32)a0 : (u32)a1;
      }
      short8 pb = *(short8*)pbw;
#pragma unroll
      for (int d0 = 0; d0 < 4; ++d0) {
        short8 va = *(const short8*)
            &Vl[(d0 * 16 + c) * 64 + (((4 * hh + g) ^ cx) << 3)];
        o[d0] = mfma16(va, pb, o[d0]);
      }
    }
    __syncthreads();
  }

  // --- normalize + write: lane holds O[q=c][d = d0*16+4g+r] ---
  float inv = 1.f / lsum;
  u16* Op = Ob + (size_t)(b * 2048 + qw + c) * 1024 + h * 64;
#pragma unroll
  for (int d0 = 0; d0 < 4; ++d0) {
    u16x4 wv;
#pragma unroll
    for (int r = 0; r < 4; ++r) wv[r] = f2bf(o[d0][r] * inv);
    *(u16x4*)(Op + d0 * 16 + 4 * g) = wv;
  }
}

// ---------------------------------------------------------------------------
extern "C" void kernel_launch(void* const* d_in, const int* in_sizes, int n_in,
                              void* d_out, int out_size, void* d_ws,
                              size_t ws_size, hipStream_t stream) {
  (void)in_sizes; (void)n_in; (void)out_size; (void)ws_size;
  const float* X = (const float*)d_in[0];
  const float* Wqkv = (const float*)d_in[1];
  const float* bqkv = (const float*)d_in[2];
  const float* Wproj = (const float*)d_in[3];
  const float* bproj = (const float*)d_in[4];
  float* out = (float*)d_out;

  char* ws = (char*)d_ws;
  u16* Xb = (u16*)ws;                          // 16 MiB [8192][1024] bf16 (also O)
  u16* WqkvT = (u16*)(ws + (16u << 20));       // 6 MiB  [3072][1024]
  u16* WprojT = (u16*)(ws + (22u << 20));      // 2 MiB  [1024][1024]
  u16* Qb = (u16*)(ws + (24u << 20));          // 16 MiB [bh][t][d], pre-scaled
  u16* Kb = (u16*)(ws + (40u << 20));          // 16 MiB [bh][t][d]
  u16* VT = (u16*)(ws + (56u << 20));          // 16 MiB [bh][d][t]

  cvt_x_kernel<<<dim3(8192), dim3(256), 0, stream>>>(
      (const float4v*)X, (u16x4*)Xb, 8192 * 1024 / 4);
  cvt_w_t_kernel<<<dim3(96, 32), dim3(32, 8), 0, stream>>>(Wqkv, WqkvT, 1024, 3072);
  cvt_w_t_kernel<<<dim3(32, 32), dim3(32, 8), 0, stream>>>(Wproj, WprojT, 1024, 1024);

  gemm_bt<0><<<dim3(24, 64), dim3(256), 0, stream>>>(
      Xb, WqkvT, bqkv, Qb, Kb, VT, (float*)nullptr, 8192, 3072, 1024);

  attn_fwd<<<dim3(2048), dim3(256), 0, stream>>>(Qb, Kb, VT, Xb);

  gemm_bt<1><<<dim3(8, 64), dim3(256), 0, stream>>>(
      Xb, WprojT, bproj, (u16*)nullptr, (u16*)nullptr, (u16*)nullptr, out,
      8192, 1024, 1024);
}

// Round 6
// 276.839 us; speedup vs baseline: 1.9223x; 1.0543x over previous
//
#include <hip/hip_runtime.h>

typedef unsigned short u16;
typedef unsigned int u32;
typedef __attribute__((ext_vector_type(8))) short short8;
typedef __attribute__((ext_vector_type(4))) float f32x4;
typedef __attribute__((ext_vector_type(4))) float float4v;
typedef __attribute__((ext_vector_type(4))) unsigned short u16x4;
typedef __attribute__((ext_vector_type(2))) u32 u32x2;

#define DEV __device__ __forceinline__

// 0.125 / ln(2): QK^T scale folded with exp->exp2 conversion
#define QSCALE 0.18033688011112042f

DEV u16 f2bf(float f) {
  u32 u = __float_as_uint(f);
  u32 r = (u + 0x7fffu + ((u >> 16) & 1u)) >> 16;
  return (u16)r;
}

// packed bf16 pair via HW cvt (RNE), lo -> bits[15:0], hi -> bits[31:16]
DEV u32 cvtpk(float lo, float hi) {
  u32 r;
  asm("v_cvt_pk_bf16_f32 %0, %1, %2" : "=v"(r) : "v"(lo), "v"(hi));
  return r;
}

DEV f32x4 mfma16(short8 a, short8 b, f32x4 c) {
  return __builtin_amdgcn_mfma_f32_16x16x32_bf16(a, b, c, 0, 0, 0);
}

DEV void gld_lds16(const void* g, void* l) {
  __builtin_amdgcn_global_load_lds(
      (const __attribute__((address_space(1))) void*)g,
      (__attribute__((address_space(3))) void*)l, 16, 0, 0);
}

// ---------------------------------------------------------------------------
// Convert X fp32 -> bf16, linear
__global__ void cvt_x_kernel(const float4v* __restrict__ in,
                             u32x2* __restrict__ out, int n4) {
  int i = blockIdx.x * blockDim.x + threadIdx.x;
  if (i >= n4) return;
  float4v v = in[i];
  u32x2 o;
  o.x = cvtpk(v.x, v.y);
  o.y = cvtpk(v.z, v.w);
  out[i] = o;
}

// Convert W fp32 [Kd][Nd] -> bf16 transposed [Nd][Kd]
__global__ void cvt_w_t_kernel(const float* __restrict__ in,
                               u16* __restrict__ out, int Kd, int Nd) {
  __shared__ float tile[32][33];
  int n0 = blockIdx.x * 32, k0 = blockIdx.y * 32;
  int tx = threadIdx.x, ty = threadIdx.y;
#pragma unroll
  for (int j = 0; j < 4; ++j)
    tile[ty + 8 * j][tx] = in[(size_t)(k0 + ty + 8 * j) * Nd + n0 + tx];
  __syncthreads();
#pragma unroll
  for (int j = 0; j < 4; ++j)
    out[(size_t)(n0 + ty + 8 * j) * Kd + k0 + tx] = f2bf(tile[tx][ty + 8 * j]);
}

// ---------------------------------------------------------------------------
// 128x128-tile bf16 GEMM, A [M][K] row-major, Bt [N][K] row-major (B^T).
// 1-D grid, XCD-swizzled (M-tile fastest within an XCD chunk -> B-panel L2
// resident per XCD). LDS chunk-XOR swizzle -> bank-even ds_read_b128.
// MODE 0: QKV epilogue -> Q [bh][t][d] (pre-scaled QSCALE), K [bh][t][d],
//         V transposed [bh][d][t], all bf16
// MODE 1: proj epilogue -> fp32 out [M][N] + bias
template <int MODE>
__global__ __launch_bounds__(256, 2) void gemm_bt(
    const u16* __restrict__ A, const u16* __restrict__ Bt,
    const float* __restrict__ bias, u16* __restrict__ q_out,
    u16* __restrict__ k_out, u16* __restrict__ vt_out,
    float* __restrict__ f_out, int M, int N, int K) {
  __shared__ u16 ldsA[128 * 64];
  __shared__ u16 ldsB[128 * 64];
  const int tid = threadIdx.x;
  const int lane = tid & 63, w = tid >> 6;
  const int g = lane >> 4, c = lane & 15;
  const int wm = w >> 1, wn = w & 1;

  // XCD-aware swizzle: grid is (N/128)*(M/128) blocks, divisible by 8.
  const int total = gridDim.x;
  const int cpx = total >> 3;
  const int wg = blockIdx.x;
  const int swz = (wg & 7) * cpx + (wg >> 3);
  const int mtiles = M >> 7;
  const int by = swz & (mtiles - 1);  // M-tile fastest (mtiles = 64, pow2)
  const int bx = swz / mtiles;
  const int n0 = bx * 128, m0 = by * 128;

  const f32x4 fz = {0.f, 0.f, 0.f, 0.f};
  f32x4 acc[4][4];
#pragma unroll
  for (int i = 0; i < 4; ++i)
#pragma unroll
    for (int j = 0; j < 4; ++j) acc[i][j] = fz;

  const u16* Ag = A + (size_t)m0 * K;
  const u16* Bg = Bt + (size_t)n0 * K;
  const int lr = lane >> 3;       // row within 8-row chunk
  const int kc = (lane & 7) ^ lr; // global k-chunk feeding swizzled LDS slot

  for (int kt = 0; kt < K; kt += 64) {
#pragma unroll
    for (int qq = 0; qq < 4; ++qq) {
      int row = w * 32 + qq * 8 + lr;
      gld_lds16(Ag + (size_t)row * K + kt + kc * 8, &ldsA[(w * 32 + qq * 8) * 64]);
      gld_lds16(Bg + (size_t)row * K + kt + kc * 8, &ldsB[(w * 32 + qq * 8) * 64]);
    }
    __syncthreads();
#pragma unroll
    for (int ks = 0; ks < 2; ++ks) {
      short8 ar[4], br[4];
#pragma unroll
      for (int mr = 0; mr < 4; ++mr) {
        int row = wm * 64 + mr * 16 + c;
        ar[mr] = *(const short8*)&ldsA[row * 64 + (((ks * 4 + g) ^ (row & 7)) << 3)];
      }
#pragma unroll
      for (int nf = 0; nf < 4; ++nf) {
        int row = wn * 64 + nf * 16 + c;
        br[nf] = *(const short8*)&ldsB[row * 64 + (((ks * 4 + g) ^ (row & 7)) << 3)];
      }
#pragma unroll
      for (int mr = 0; mr < 4; ++mr)
#pragma unroll
        for (int nf = 0; nf < 4; ++nf)
          acc[mr][nf] = mfma16(ar[mr], br[nf], acc[mr][nf]);
    }
    __syncthreads();
  }

#pragma unroll
  for (int mr = 0; mr < 4; ++mr) {
#pragma unroll
    for (int nf = 0; nf < 4; ++nf) {
      const int gm0 = m0 + wm * 64 + mr * 16 + 4 * g;
      const int gn = n0 + wn * 64 + nf * 16 + c;
      float v4[4];
#pragma unroll
      for (int r = 0; r < 4; ++r) v4[r] = acc[mr][nf][r] + bias[gn];
      if (MODE == 0) {
        const int sec = gn >> 10, cc = gn & 1023;
        const int hh = cc >> 6, dd = cc & 63;
        const int bb = gm0 >> 11, tt0 = gm0 & 2047;
        if (sec == 0) {
#pragma unroll
          for (int r = 0; r < 4; ++r)
            q_out[((size_t)(bb * 16 + hh) * 2048 + tt0 + r) * 64 + dd] =
                f2bf(v4[r] * QSCALE);
        } else if (sec == 1) {
#pragma unroll
          for (int r = 0; r < 4; ++r)
            k_out[((size_t)(bb * 16 + hh) * 2048 + tt0 + r) * 64 + dd] =
                f2bf(v4[r]);
        } else {
          // V^T: r -> consecutive t, one 8B packed store
          u32x2 pkd;
          pkd.x = cvtpk(v4[0], v4[1]);
          pkd.y = cvtpk(v4[2], v4[3]);
          *(u32x2*)&vt_out[((size_t)(bb * 16 + hh) * 64 + dd) * 2048 + tt0] = pkd;
        }
      } else {
#pragma unroll
        for (int r = 0; r < 4; ++r)
          f_out[(size_t)(gm0 + r) * N + gn] = v4[r];
      }
    }
  }
}

// ---------------------------------------------------------------------------
// Flash attention fwd, causal. Block = 64 queries of one (b,h); 4 waves x 16q.
// K tile [64k][64d] + V^T tile [64d][64k] LDS-staged, double-buffered,
// chunk-XOR swizzled. Swapped QK^T -> softmax state lane-local (q = lane&15).
// PV: o^T = mfma(V^Tfrag, Pfrag). Q pre-scaled 0.125/ln2; exp2 softmax;
// defer-max rescale (THR=8 in log2 domain).
__global__ __launch_bounds__(256, 5) void attn_fwd(
    const u16* __restrict__ Qb, const u16* __restrict__ Kb,
    const u16* __restrict__ VTb, u16* __restrict__ Ob) {
  __shared__ u16 lds[2][8192];  // per buf: K at [0..4095], VT at [4096..8191]
  const int lane = threadIdx.x & 63, w = threadIdx.x >> 6;
  const int g = lane >> 4, c = lane & 15;
  const int bi = blockIdx.x;
  const int bh = ((bi & 7) << 3) | ((bi >> 3) & 7);  // 8 heads per XCD
  const int qblock = 31 - (bi >> 6);                 // longest blocks first
  const int b = bh >> 4, h = bh & 15;
  const size_t base = (size_t)bh * (2048 * 64);
  const u16* Qp = Qb + base;
  const u16* Kp = Kb + base;
  const u16* VTp = VTb + base;

  const int qw = qblock * 64 + w * 16;  // wave's first query
  const int qg = qw + c;                // this lane's query
  const int nt = qblock + 1;

  short8 qf0 = *(const short8*)&Qp[(qw + c) * 64 + g * 8];
  short8 qf1 = *(const short8*)&Qp[(qw + c) * 64 + 32 + g * 8];

  const f32x4 fz = {0.f, 0.f, 0.f, 0.f};
  f32x4 o[4];
#pragma unroll
  for (int d0 = 0; d0 < 4; ++d0) o[d0] = fz;
  float m = -1e30f, lsum = 0.f;

  // staging: 16 wave-calls of 1KB; region i<8 = K rows 8i..8i+7, i>=8 = VT rows
  const int srow = lane >> 3;                    // row within 8-row region
  const int sgx = (lane & 7) ^ (srow & 7);       // pre-swizzled global chunk
  auto stage = [&](int t, int buf) {
#pragma unroll
    for (int q = 0; q < 4; ++q) {
      const int i = w * 4 + q;
      const int row = ((i & 7) << 3) | srow;
      const int k0 = t << 6;
      const u16* src = (i < 8)
          ? Kp + (size_t)(k0 + row) * 64 + sgx * 8
          : VTp + (size_t)row * 2048 + k0 + sgx * 8;
      gld_lds16(src, &lds[buf][i * 512]);
    }
  };

  stage(0, 0);
  __syncthreads();

  for (int t = 0; t < nt; ++t) {
    const int cur = t & 1;
    if (t + 1 < nt) stage(t + 1, cur ^ 1);
    const u16* Kl = &lds[cur][0];
    const u16* Vl = &lds[cur][4096];
    const int k0b = t << 6;
    const int cx = c & 7;

    // --- QK^T: 64 keys x 16 queries ---
    float pv[16];
#pragma unroll
    for (int j = 0; j < 4; ++j) {
      short8 ka = *(const short8*)&Kl[(16 * j + c) * 64 + ((g ^ cx) << 3)];
      short8 kb = *(const short8*)&Kl[(16 * j + c) * 64 + (((4 + g) ^ cx) << 3)];
      f32x4 s = mfma16(ka, qf0, fz);
      s = mfma16(kb, qf1, s);
#pragma unroll
      for (int r = 0; r < 4; ++r) pv[j * 4 + r] = s[r];
    }

    if (t == nt - 1) {  // only last tile can contain masked keys
#pragma unroll
      for (int j = 0; j < 4; ++j)
#pragma unroll
        for (int r = 0; r < 4; ++r)
          if (k0b + 16 * j + 4 * g + r > qg) pv[j * 4 + r] = -1e30f;
    }

    // --- online softmax (state lane-local: q = c), tree reductions ---
    float mx[8];
#pragma unroll
    for (int i = 0; i < 8; ++i) mx[i] = fmaxf(pv[2 * i], pv[2 * i + 1]);
#pragma unroll
    for (int i = 0; i < 4; ++i) mx[i] = fmaxf(mx[i], mx[i + 4]);
    float tm = fmaxf(fmaxf(mx[0], mx[1]), fmaxf(mx[2], mx[3]));
    tm = fmaxf(tm, __shfl_xor(tm, 16));
    tm = fmaxf(tm, __shfl_xor(tm, 32));

    // defer-max: only rescale when some lane's max grew past THR=8 (log2)
    if (__any(tm > m + 8.f)) {
      float mn = fmaxf(m, tm);
      float sc = __builtin_amdgcn_exp2f(m - mn);
      m = mn;
      lsum *= sc;
#pragma unroll
      for (int d0 = 0; d0 < 4; ++d0)
#pragma unroll
        for (int r = 0; r < 4; ++r) o[d0][r] *= sc;
    }

#pragma unroll
    for (int i = 0; i < 16; ++i) pv[i] = __builtin_amdgcn_exp2f(pv[i] - m);
    float sx[8];
#pragma unroll
    for (int i = 0; i < 8; ++i) sx[i] = pv[2 * i] + pv[2 * i + 1];
#pragma unroll
    for (int i = 0; i < 4; ++i) sx[i] = sx[i] + sx[i + 4];
    float rs = (sx[0] + sx[1]) + (sx[2] + sx[3]);
    rs += __shfl_xor(rs, 16);
    rs += __shfl_xor(rs, 32);
    lsum += rs;

    // --- pack P to bf16 pairs: P2[j*2+rr] = keys (16j+4g+2rr, +1) ---
    u32 P2[8];
#pragma unroll
    for (int j = 0; j < 4; ++j) {
      P2[j * 2 + 0] = cvtpk(pv[j * 4 + 0], pv[j * 4 + 1]);
      P2[j * 2 + 1] = cvtpk(pv[j * 4 + 2], pv[j * 4 + 3]);
    }

    // --- PV: o^T += V^T @ P, 2 key-halves x 4 d-blocks ---
#pragma unroll
    for (int hh = 0; hh < 2; ++hh) {
      u32 pbw[4];
#pragma unroll
      for (int i = 0; i < 4; ++i) {
        int src = c + ((2 * (g & 1) + (i >> 1)) << 4);
        int a0 = __shfl((int)P2[(2 * hh) * 2 + (i & 1)], src);
        int a1 = __shfl((int)P2[(2 * hh + 1) * 2 + (i & 1)], src);
        pbw[i] = (g < 2) ? (u32)a0 : (u32)a1;
      }
      short8 pb = *(short8*)pbw;
#pragma unroll
      for (int d0 = 0; d0 < 4; ++d0) {
        short8 va = *(const short8*)
            &Vl[(d0 * 16 + c) * 64 + (((4 * hh + g) ^ cx) << 3)];
        o[d0] = mfma16(va, pb, o[d0]);
      }
    }
    __syncthreads();
  }

  // --- normalize + write: lane holds O[q=c][d = d0*16+4g+r] ---
  float inv = 1.f / lsum;
  u16* Op = Ob + (size_t)(b * 2048 + qw + c) * 1024 + h * 64;
#pragma unroll
  for (int d0 = 0; d0 < 4; ++d0) {
    u32x2 pk;
    pk.x = cvtpk(o[d0][0] * inv, o[d0][1] * inv);
    pk.y = cvtpk(o[d0][2] * inv, o[d0][3] * inv);
    *(u32x2*)(Op + d0 * 16 + 4 * g) = pk;
  }
}

// ---------------------------------------------------------------------------
extern "C" void kernel_launch(void* const* d_in, const int* in_sizes, int n_in,
                              void* d_out, int out_size, void* d_ws,
                              size_t ws_size, hipStream_t stream) {
  (void)in_sizes; (void)n_in; (void)out_size; (void)ws_size;
  const float* X = (const float*)d_in[0];
  const float* Wqkv = (const float*)d_in[1];
  const float* bqkv = (const float*)d_in[2];
  const float* Wproj = (const float*)d_in[3];
  const float* bproj = (const float*)d_in[4];
  float* out = (float*)d_out;

  char* ws = (char*)d_ws;
  u16* Xb = (u16*)ws;                          // 16 MiB [8192][1024] bf16 (also O)
  u16* WqkvT = (u16*)(ws + (16u << 20));       // 6 MiB  [3072][1024]
  u16* WprojT = (u16*)(ws + (22u << 20));      // 2 MiB  [1024][1024]
  u16* Qb = (u16*)(ws + (24u << 20));          // 16 MiB [bh][t][d], pre-scaled
  u16* Kb = (u16*)(ws + (40u << 20));          // 16 MiB [bh][t][d]
  u16* VT = (u16*)(ws + (56u << 20));          // 16 MiB [bh][d][t]

  cvt_x_kernel<<<dim3(8192), dim3(256), 0, stream>>>(
      (const float4v*)X, (u32x2*)Xb, 8192 * 1024 / 4);
  cvt_w_t_kernel<<<dim3(96, 32), dim3(32, 8), 0, stream>>>(Wqkv, WqkvT, 1024, 3072);
  cvt_w_t_kernel<<<dim3(32, 32), dim3(32, 8), 0, stream>>>(Wproj, WprojT, 1024, 1024);

  gemm_bt<0><<<dim3(1536), dim3(256), 0, stream>>>(
      Xb, WqkvT, bqkv, Qb, Kb, VT, (float*)nullptr, 8192, 3072, 1024);

  attn_fwd<<<dim3(2048), dim3(256), 0, stream>>>(Qb, Kb, VT, Xb);

  gemm_bt<1><<<dim3(512), dim3(256), 0, stream>>>(
      Xb, WprojT, bproj, (u16*)nullptr, (u16*)nullptr, (u16*)nullptr, out,
      8192, 1024, 1024);
}